// Round 9
// baseline (307.886 us; speedup 1.0000x reference)
//
#include <hip/hip_runtime.h>
#include <math.h>

// ---- Problem constants (fixed by the reference) ----
constexpr int BATCH = 262144;
constexpr int M_  = 2;
constexpr int N_  = 4;
constexpr int NB_ = 5;
constexpr int NH_ = 8;
constexpr int HD_ = 4;
constexpr int HID_ = 32;
constexpr float D_v    = 50.0f;
constexpr float HZ_v   = 5.0f;
constexpr float DMIN_v = 0.025f;
constexpr float PMAX_v = 1.0f;
constexpr float SCALE_v = 0.5f;                            // 1/sqrt(HD)
constexpr float BMAX_v  = 2.0f * D_v - (N_ - 1) * DMIN_v;  // 99.925
constexpr float LOG2E_v = 1.44269504088896340736f;

// ---- Packed-weight layout in d_ws (float offsets) ----
// HP  [5][8][32]     : per (layer,head), de-interleaved:
//                      wu_e4 | wu_o4 | wa_e4 | wa_o4 | we4 | av*SCALE*log2e 4 | wres0 4 | wres1 4
// W1G [5][2][32][16] : w1 transposed, LN gain folded ([d][br][col][j])
// SGB [5][4][16]     : per d: G_mu | B_mu | G_ma | B_ma (G=sum g*w1, B=sum b*w1+b1)
// W2  [5][2][40]     : w2 row0(16) | row1(16) | b2(2) | pad(6)
// RO  [160]          : rd_w1 rd_b1 rd_w2 rd_b2 rp_w1 rp_b1 rp_w2 rp_b2 pad
constexpr int HP_OFF  = 0;      // 1280
constexpr int W1G_OFF = 1280;   // 5120
constexpr int SGB_OFF = 6400;   // 320
constexpr int W2_OFF  = 6720;   // 400
constexpr int RO_OFF  = 7120;   // 160
constexpr int TOTF    = 7280;

typedef __attribute__((ext_vector_type(2))) float f2;

__device__ __forceinline__ float frcp(float x) { return __builtin_amdgcn_rcpf(x); }
__device__ __forceinline__ float fexp2(float x) { float d; asm("v_exp_f32 %0, %1" : "=v"(d) : "v"(x)); return d; }
__device__ __forceinline__ float fsqrt_(float x) { float d; asm("v_sqrt_f32 %0, %1" : "=v"(d) : "v"(x)); return d; }
__device__ __forceinline__ float frsq_(float x) { float d; asm("v_rsq_f32 %0, %1" : "=v"(d) : "v"(x)); return d; }

// ---- VOP3P packed-fp32 with op_sel broadcasts (HW-verified by R8: passed
// with identical absmax). bc = both halves read the same dword of that src.
// Tied "+v" accumulators => zero copy; broadcasts from fully-live pairs =>
// zero v_mov (R7's regression was exactly those two taxes).
__device__ __forceinline__ f2 pk_add_vv(f2 a, f2 b) { f2 d; asm("v_pk_add_f32 %0, %1, %2" : "=v"(d) : "v"(a), "v"(b)); return d; }
__device__ __forceinline__ f2 pk_mul_vv(f2 a, f2 b) { f2 d; asm("v_pk_mul_f32 %0, %1, %2" : "=v"(d) : "v"(a), "v"(b)); return d; }
__device__ __forceinline__ f2 pk_mul_sv(f2 as, f2 b) { f2 d; asm("v_pk_mul_f32 %0, %1, %2" : "=v"(d) : "s"(as), "v"(b)); return d; }
__device__ __forceinline__ f2 pk_mul_bl_s(f2 a, f2 bs) { f2 d; asm("v_pk_mul_f32 %0, %1, %2 op_sel:[0,0] op_sel_hi:[0,1]" : "=v"(d) : "v"(a), "s"(bs)); return d; }
__device__ __forceinline__ f2 pk_mul_bh_s(f2 a, f2 bs) { f2 d; asm("v_pk_mul_f32 %0, %1, %2 op_sel:[1,0] op_sel_hi:[1,1]" : "=v"(d) : "v"(a), "s"(bs)); return d; }
__device__ __forceinline__ f2 pk_mul_bl_v(f2 a, f2 b) { f2 d; asm("v_pk_mul_f32 %0, %1, %2 op_sel:[0,0] op_sel_hi:[0,1]" : "=v"(d) : "v"(a), "v"(b)); return d; }
__device__ __forceinline__ f2 pk_mul_bh_v(f2 a, f2 b) { f2 d; asm("v_pk_mul_f32 %0, %1, %2 op_sel:[1,0] op_sel_hi:[1,1]" : "=v"(d) : "v"(a), "v"(b)); return d; }
__device__ __forceinline__ void pk_fma_bl_s_acc(f2& acc, f2 a, f2 bs) { asm("v_pk_fma_f32 %0, %1, %2, %0 op_sel:[0,0,0] op_sel_hi:[0,1,1]" : "+v"(acc) : "v"(a), "s"(bs)); }
__device__ __forceinline__ void pk_fma_bh_s_acc(f2& acc, f2 a, f2 bs) { asm("v_pk_fma_f32 %0, %1, %2, %0 op_sel:[1,0,0] op_sel_hi:[1,1,1]" : "+v"(acc) : "v"(a), "s"(bs)); }
__device__ __forceinline__ void pk_fma_bl_v_acc(f2& acc, f2 a, f2 b) { asm("v_pk_fma_f32 %0, %1, %2, %0 op_sel:[0,0,0] op_sel_hi:[0,1,1]" : "+v"(acc) : "v"(a), "v"(b)); }
__device__ __forceinline__ void pk_fma_bh_v_acc(f2& acc, f2 a, f2 b) { asm("v_pk_fma_f32 %0, %1, %2, %0 op_sel:[1,0,0] op_sel_hi:[1,1,1]" : "+v"(acc) : "v"(a), "v"(b)); }
__device__ __forceinline__ void pk_fma_s_acc(f2& acc, f2 as, f2 b) { asm("v_pk_fma_f32 %0, %1, %2, %0" : "+v"(acc) : "s"(as), "v"(b)); }
__device__ __forceinline__ void pk_fma_v_acc(f2& acc, f2 a, f2 b) { asm("v_pk_fma_f32 %0, %1, %2, %0" : "+v"(acc) : "v"(a), "v"(b)); }
__device__ __forceinline__ void pk_add_acc(f2& acc, f2 a) { asm("v_pk_add_f32 %0, %1, %0" : "+v"(acc) : "v"(a)); }
__device__ __forceinline__ f2 pk_fma_bh_vs(f2 a, f2 b, f2 cs) { f2 d; asm("v_pk_fma_f32 %0, %1, %2, %3 op_sel:[1,0,0] op_sel_hi:[1,1,1]" : "=v"(d) : "v"(a), "v"(b), "s"(cs)); return d; }
// w1 matvec (R8): acc.lo += w.lo*x.sel ; acc.hi += w.hi*x.sel
__device__ __forceinline__ void pk_fma_wlo(f2& acc, f2 w, f2 x) {
    asm("v_pk_fma_f32 %0, %1, %2, %0 op_sel:[0,0,0] op_sel_hi:[1,0,1]" : "+v"(acc) : "s"(w), "v"(x));
}
__device__ __forceinline__ void pk_fma_whi(f2& acc, f2 w, f2 x) {
    asm("v_pk_fma_f32 %0, %1, %2, %0 op_sel:[0,1,0] op_sel_hi:[1,1,1]" : "+v"(acc) : "s"(w), "v"(x));
}

__global__ __launch_bounds__(256) void pack_weights(
    const float* __restrict__ Wu, const float* __restrict__ Wa, const float* __restrict__ We,
    const float* __restrict__ av, const float* __restrict__ Wres,
    const float* __restrict__ lnu_g, const float* __restrict__ lnu_b,
    const float* __restrict__ lna_g, const float* __restrict__ lna_b,
    const float* __restrict__ mu_w1, const float* __restrict__ mu_b1,
    const float* __restrict__ mu_w2, const float* __restrict__ mu_b2,
    const float* __restrict__ ma_w1, const float* __restrict__ ma_b1,
    const float* __restrict__ ma_w2, const float* __restrict__ ma_b2,
    const float* __restrict__ rd_w1, const float* __restrict__ rd_b1,
    const float* __restrict__ rd_w2, const float* __restrict__ rd_b2,
    const float* __restrict__ rp_w1, const float* __restrict__ rp_b1,
    const float* __restrict__ rp_w2, const float* __restrict__ rp_b2,
    float* __restrict__ ws)
{
    const int gid = blockIdx.x * 256 + threadIdx.x;
    if (gid >= TOTF) return;

    if (gid < HP_OFF + 1280) {
        const int idx = gid - HP_OFF;
        const int d = idx >> 8, r = idx & 255, k = r >> 5, s = r & 31;
        const int dk = d * 8 + k;
        float v;
        if      (s <  4) v = Wu[dk * 8 + 2 * s];
        else if (s <  8) v = Wu[dk * 8 + 2 * (s - 4) + 1];
        else if (s < 12) v = Wa[dk * 8 + 2 * (s - 8)];
        else if (s < 16) v = Wa[dk * 8 + 2 * (s - 12) + 1];
        else if (s < 20) v = We[dk * 4 + (s - 16)];
        else if (s < 24) v = av[dk * 4 + (s - 20)] * (SCALE_v * LOG2E_v);  // base-2 softmax fold
        else if (s < 28) v = Wres[(d * 32 + k * 4 + (s - 24)) * 2 + 0];
        else             v = Wres[(d * 32 + k * 4 + (s - 28)) * 2 + 1];
        ws[gid] = v;
    } else if (gid < W1G_OFF + 5120) {
        const int idx = gid - W1G_OFF;
        const int d = idx >> 10, r = idx & 1023, br = r >> 9, r2 = r & 511;
        const int col = r2 >> 4, j = r2 & 15;
        const float* w1 = br ? ma_w1 : mu_w1;
        const float* g  = br ? lna_g : lnu_g;
        ws[gid] = w1[(d * 16 + j) * 32 + col] * g[d * 32 + col];
    } else if (gid < SGB_OFF + 320) {
        const int idx = gid - SGB_OFF;
        const int d = idx >> 6, r = idx & 63, q = r >> 4, j = r & 15;
        const int br = q >> 1, gb = q & 1;
        const float* w1 = (br ? ma_w1 : mu_w1) + (d * 16 + j) * 32;
        const float* gv = (br ? lna_g : lnu_g) + d * 32;
        const float* bv = (br ? lna_b : lnu_b) + d * 32;
        float acc = 0.f;
        if (gb == 0) { for (int i = 0; i < 32; ++i) acc = fmaf(gv[i], w1[i], acc); }
        else {
            for (int i = 0; i < 32; ++i) acc = fmaf(bv[i], w1[i], acc);
            acc += (br ? ma_b1 : mu_b1)[d * 16 + j];
        }
        ws[gid] = acc;
    } else if (gid < W2_OFF + 400) {
        const int idx = gid - W2_OFF;
        const int d = idx / 80, r = idx % 80, br = r / 40, s = r % 40;
        const float* w2 = br ? ma_w2 : mu_w2;
        const float* b2 = br ? ma_b2 : mu_b2;
        float v = 0.f;
        if (s < 32) v = w2[d * 32 + s];
        else if (s < 34) v = b2[d * 2 + (s - 32)];
        ws[gid] = v;
    } else {
        const int idx = gid - RO_OFF;
        float v = 0.f;
        if      (idx <  32) v = rd_w1[idx];
        else if (idx <  40) v = rd_b1[idx - 32];
        else if (idx <  72) v = rd_w2[idx - 40];
        else if (idx <  76) v = rd_b2[idx - 72];
        else if (idx < 108) v = rp_w1[idx - 76];
        else if (idx < 116) v = rp_b1[idx - 108];
        else if (idx < 148) v = rp_w2[idx - 116];
        else if (idx < 152) v = rp_b2[idx - 148];
        ws[gid] = v;
    }
}

// One thread = one batch element. Weights via wave-uniform s_load (zero LDS).
// ALL lane-varying state lives in fully-populated f2 pairs; every broadcast
// is an op_sel on a live pair (free). Every hot op is VOP3P (2 FLOP/slot).
__global__ __launch_bounds__(256) void bgat_fwd(
    const float* __restrict__ ws,
    const float* __restrict__ users, const float* __restrict__ delta_init,
    const float* __restrict__ power_init, float* __restrict__ out)
{
    const int b = blockIdx.x * 256 + threadIdx.x;

    f2 ufp[M_];   // (x, y) per user
    {
        const float4 u = ((const float4*)users)[b];
        ufp[0].x = u.x; ufp[0].y = u.y; ufp[1].x = u.z; ufp[1].y = u.w;
    }
    f2 afp[N_];   // (power, delta) per node
    {
        const float4 p  = ((const float4*)power_init)[b];
        const float4 dl = ((const float4*)delta_init)[b];
        afp[0].x = p.x;  afp[1].x = p.y;  afp[2].x = p.z;  afp[3].x = p.w;
        afp[0].y = dl.x; afp[1].y = dl.y; afp[2].y = dl.z; afp[3].y = dl.w;
    }
    const f2 lr02 = {0.2f, 0.2f};

#pragma unroll 1
    for (int d = 0; d < NB_; ++d) {
        const float* hpL  = ws + HP_OFF  + d * 256;
        const float* w1uL = ws + W1G_OFF + d * 1024;     // br=0; br=1 at +512
        const float* gbL  = ws + SGB_OFF + d * 64;
        const float* w2L  = ws + W2_OFF  + d * 80;

        // ---- node positions & edges ----
        float sd = 1e-6f;
        float da[N_];
#pragma unroll
        for (int n = 0; n < N_; ++n) { da[n] = fmaxf(afp[n].y, 0.f); sd += da[n]; }
        const float rs = BMAX_v * frcp(sd);
        float xpos[N_];
        {
            float cum = 0.f;
#pragma unroll
            for (int n = 0; n < N_; ++n) {
                cum = fmaf(rs, da[n], cum);
                xpos[n] = cum - D_v + DMIN_v * (float)n;
            }
        }
        f2 e01[M_], e23[M_];   // edges: (n0,n1), (n2,n3) per m
#pragma unroll
        for (int m = 0; m < M_; ++m) {
            const float dy2 = ufp[m].y * ufp[m].y;
#pragma unroll
            for (int n = 0; n < N_; ++n) {
                const float dx = ufp[m].x - xpos[n];
                const float e = fsqrt_(fmaf(dx, dx, dy2));
                if (n == 0) e01[m].x = e; else if (n == 1) e01[m].y = e;
                else if (n == 2) e23[m].x = e; else e23[m].y = e;
            }
        }

        // ---- deferred-LN accumulators (pairs over j) ----
        f2 Smu[M_][8], Sma[N_][8];
        f2 sxu2[M_], sxxu2[M_], sxa2[N_], sxxa2[N_];
#pragma unroll
        for (int m = 0; m < M_; ++m) {
            sxu2[m] = (f2){0.f, 0.f}; sxxu2[m] = (f2){0.f, 0.f};
#pragma unroll
            for (int j = 0; j < 8; ++j) Smu[m][j] = (f2){0.f, 0.f};
        }
#pragma unroll
        for (int n = 0; n < N_; ++n) {
            sxa2[n] = (f2){0.f, 0.f}; sxxa2[n] = (f2){0.f, 0.f};
#pragma unroll
            for (int j = 0; j < 8; ++j) Sma[n][j] = (f2){0.f, 0.f};
        }

        // ---- attention heads ----
#pragma unroll 1
        for (int k = 0; k < NH_; ++k) {
            const f2* hp2 = (const f2*)(hpL + k * 32);
            const f2 wue[2] = {hp2[0],  hp2[1]};
            const f2 wuo[2] = {hp2[2],  hp2[3]};
            const f2 wae[2] = {hp2[4],  hp2[5]};
            const f2 wao[2] = {hp2[6],  hp2[7]};
            const f2 we2[2] = {hp2[8],  hp2[9]};
            const f2 av2[2] = {hp2[10], hp2[11]};   // av*SCALE*log2e
            const f2 wr0[2] = {hp2[12], hp2[13]};
            const f2 wr1[2] = {hp2[14], hp2[15]};

            // U/A projections: p = head-dim pair (2p,2p+1); bc from ufp/afp
            f2 U2[M_][2], A2[N_][2];
#pragma unroll
            for (int p = 0; p < 2; ++p) {
#pragma unroll
                for (int m = 0; m < M_; ++m) {
                    f2 t = pk_mul_bh_s(ufp[m], wuo[p]);
                    pk_fma_bl_s_acc(t, ufp[m], wue[p]);
                    U2[m][p] = t;
                }
#pragma unroll
                for (int n = 0; n < N_; ++n) {
                    f2 t = pk_mul_bh_s(afp[n], wao[p]);
                    pk_fma_bl_s_acc(t, afp[n], wae[p]);
                    A2[n][p] = t;
                }
            }

            // scores + base-2 softmax
            f2 ex01[M_], ex23[M_], rdp;
#pragma unroll
            for (int m = 0; m < M_; ++m) {
                float sc[N_];
#pragma unroll
                for (int n = 0; n < N_; ++n) {
                    const f2 ep = (n < 2) ? e01[m] : e23[m];
                    f2 t0 = pk_add_vv(U2[m][0], A2[n][0]);
                    if (n & 1) pk_fma_bh_s_acc(t0, ep, we2[0]); else pk_fma_bl_s_acc(t0, ep, we2[0]);
                    f2 q0 = pk_mul_vv(t0, lr02);
                    t0.x = fmaxf(t0.x, q0.x); t0.y = fmaxf(t0.y, q0.y);   // leaky_relu
                    f2 s2 = pk_mul_sv(av2[0], t0);
                    f2 t1 = pk_add_vv(U2[m][1], A2[n][1]);
                    if (n & 1) pk_fma_bh_s_acc(t1, ep, we2[1]); else pk_fma_bl_s_acc(t1, ep, we2[1]);
                    f2 q1 = pk_mul_vv(t1, lr02);
                    t1.x = fmaxf(t1.x, q1.x); t1.y = fmaxf(t1.y, q1.y);
                    pk_fma_s_acc(s2, av2[1], t1);
                    sc[n] = s2.x + s2.y;
                }
                const float mx = fmaxf(fmaxf(sc[0], sc[1]), fmaxf(sc[2], sc[3]));
                const float e0 = fexp2(sc[0] - mx), e1 = fexp2(sc[1] - mx);
                const float e2v = fexp2(sc[2] - mx), e3 = fexp2(sc[3] - mx);
                ex01[m].x = e0; ex01[m].y = e1; ex23[m].x = e2v; ex23[m].y = e3;
                const float den = (e0 + e1) + (e2v + e3);
                if (m == 0) rdp.x = frcp(den); else rdp.y = frcp(den);
            }
            f2 al01[M_], al23[M_];
            al01[0] = pk_mul_bl_v(rdp, ex01[0]); al23[0] = pk_mul_bl_v(rdp, ex23[0]);
            al01[1] = pk_mul_bh_v(rdp, ex01[1]); al23[1] = pk_mul_bh_v(rdp, ex23[1]);

            // edge-weighted alpha sums: eaup = (eau0, eau1); ean pairs
            f2 eaup, ean01, ean23;
            {
                f2 pp0 = pk_mul_vv(e01[0], al01[0]); pk_fma_v_acc(pp0, e23[0], al23[0]);
                f2 pp1 = pk_mul_vv(e01[1], al01[1]); pk_fma_v_acc(pp1, e23[1], al23[1]);
                eaup.x = pp0.x + pp0.y; eaup.y = pp1.x + pp1.y;
                ean01.x = fmaf(e01[0].x, al01[0].x, e01[1].x * al01[1].x);
                ean01.y = fmaf(e01[0].y, al01[0].y, e01[1].y * al01[1].y);
                ean23.x = fmaf(e23[0].x, al23[0].x, e23[1].x * al23[1].x);
                ean23.y = fmaf(e23[0].y, al23[0].y, e23[1].y * al23[1].y);
            }

            // aggregation + w1 matvec; p covers cols k*4+2p, k*4+2p+1
#pragma unroll
            for (int p = 0; p < 2; ++p) {
                const int c0 = k * 4 + 2 * p;
                const f2* wc0u = (const f2*)(w1uL + c0 * 16);
                const f2* wc1u = wc0u + 8;
                const f2* wc0a = (const f2*)(w1uL + 512 + c0 * 16);
                const f2* wc1a = wc0a + 8;

                // --- user rows ---
#pragma unroll
                for (int m = 0; m < M_; ++m) {
                    f2 uo = (m == 0) ? pk_mul_bl_s(eaup, we2[p]) : pk_mul_bh_s(eaup, we2[p]);
                    pk_fma_bl_v_acc(uo, al01[m], A2[0][p]);
                    pk_fma_bh_v_acc(uo, al01[m], A2[1][p]);
                    pk_fma_bl_v_acc(uo, al23[m], A2[2][p]);
                    pk_fma_bh_v_acc(uo, al23[m], A2[3][p]);
                    pk_fma_bl_s_acc(uo, ufp[m], wr0[p]);
                    pk_fma_bh_s_acc(uo, ufp[m], wr1[p]);
                    pk_add_acc(sxu2[m], uo);
                    pk_fma_v_acc(sxxu2[m], uo, uo);
#pragma unroll
                    for (int j = 0; j < 8; ++j) {
                        pk_fma_wlo(Smu[m][j], wc0u[j], uo);
                        pk_fma_whi(Smu[m][j], wc1u[j], uo);
                    }
                }
                // --- node rows ---
#pragma unroll
                for (int n = 0; n < N_; ++n) {
                    const f2 eap = (n < 2) ? ean01 : ean23;
                    const f2 a0p = (n < 2) ? al01[0] : al23[0];
                    const f2 a1p = (n < 2) ? al01[1] : al23[1];
                    f2 xa = (n & 1) ? pk_mul_bh_s(eap, we2[p]) : pk_mul_bl_s(eap, we2[p]);
                    if (n & 1) { pk_fma_bh_v_acc(xa, a0p, U2[0][p]); pk_fma_bh_v_acc(xa, a1p, U2[1][p]); }
                    else       { pk_fma_bl_v_acc(xa, a0p, U2[0][p]); pk_fma_bl_v_acc(xa, a1p, U2[1][p]); }
                    pk_add_acc(sxa2[n], xa);
                    pk_fma_v_acc(sxxa2[n], xa, xa);
#pragma unroll
                    for (int j = 0; j < 8; ++j) {
                        pk_fma_wlo(Sma[n][j], wc0a[j], xa);
                        pk_fma_whi(Sma[n][j], wc1a[j], xa);
                    }
                }
            }
        } // heads

        // ---- MLPs with LN folded (packed over j; stat pair = (-mu, inv)) ----
        const f2* Gmu2 = (const f2*)(gbL);
        const f2* Bmu2 = (const f2*)(gbL + 16);
        const f2* Gma2 = (const f2*)(gbL + 32);
        const f2* Bma2 = (const f2*)(gbL + 48);
        const f2* w2u0 = (const f2*)(w2L);
        const f2* w2u1 = (const f2*)(w2L + 16);
        const f2* w2a0 = (const f2*)(w2L + 40);
        const f2* w2a1 = (const f2*)(w2L + 56);

        f2 nufp[M_], nafp[N_];
#pragma unroll
        for (int m = 0; m < M_; ++m) {
            const float sx = sxu2[m].x + sxu2[m].y;
            const float sxx = sxxu2[m].x + sxxu2[m].y;
            const float mu_ = sx * (1.0f / HID_);
            const float var = sxx * (1.0f / HID_) - mu_ * mu_;
            const float inv = frsq_(var + 1e-5f);
            f2 statp; statp.x = -mu_; statp.y = inv;
            f2 o0 = (f2){0.f, 0.f}, o1 = (f2){0.f, 0.f};
#pragma unroll
            for (int j = 0; j < 8; ++j) {
                pk_fma_bl_s_acc(Smu[m][j], statp, Gmu2[j]);          // S' = -mu*G + S
                f2 pre = pk_fma_bh_vs(statp, Smu[m][j], Bmu2[j]);    // inv*S' + B
                pre.x = fmaxf(pre.x, 0.f); pre.y = fmaxf(pre.y, 0.f);
                pk_fma_s_acc(o0, w2u0[j], pre);
                pk_fma_s_acc(o1, w2u1[j], pre);
            }
            nufp[m].x = o0.x + o0.y + w2L[32];
            nufp[m].y = o1.x + o1.y + w2L[33];
        }
#pragma unroll
        for (int n = 0; n < N_; ++n) {
            const float sx = sxa2[n].x + sxa2[n].y;
            const float sxx = sxxa2[n].x + sxxa2[n].y;
            const float mu_ = sx * (1.0f / HID_);
            const float var = sxx * (1.0f / HID_) - mu_ * mu_;
            const float inv = frsq_(var + 1e-5f);
            f2 statp; statp.x = -mu_; statp.y = inv;
            f2 o0 = (f2){0.f, 0.f}, o1 = (f2){0.f, 0.f};
#pragma unroll
            for (int j = 0; j < 8; ++j) {
                pk_fma_bl_s_acc(Sma[n][j], statp, Gma2[j]);
                f2 pre = pk_fma_bh_vs(statp, Sma[n][j], Bma2[j]);
                pre.x = fmaxf(pre.x, 0.f); pre.y = fmaxf(pre.y, 0.f);
                pk_fma_s_acc(o0, w2a0[j], pre);
                pk_fma_s_acc(o1, w2a1[j], pre);
            }
            nafp[n].x = o0.x + o0.y + w2L[72];
            nafp[n].y = o1.x + o1.y + w2L[73];
        }
#pragma unroll
        for (int m = 0; m < M_; ++m) ufp[m] = nufp[m];
#pragma unroll
        for (int n = 0; n < N_; ++n) afp[n] = nafp[n];
    } // layers

    const float* ro = ws + RO_OFF;

    // ---- delta readout (af[.][1] = afp.y) ----
    float hid[8];
#pragma unroll
    for (int j = 0; j < 8; ++j) {
        float s = ro[32 + j];
#pragma unroll
        for (int n = 0; n < N_; ++n) s = fmaf(afp[n].y, ro[j * 4 + n], s);
        hid[j] = fmaxf(s, 0.f);
    }
    float daux[N_];
    float sumd = 0.f;
#pragma unroll
    for (int n = 0; n < N_; ++n) {
        float s = ro[72 + n];
#pragma unroll
        for (int j = 0; j < 8; ++j) s = fmaf(hid[j], ro[40 + n * 8 + j], s);
        daux[n] = fmaxf(s, 0.001f);
        sumd += daux[n];
    }
    const float sdl = BMAX_v * frcp(sumd);
    float sdelta[N_], xf[N_];
    {
        float cum = 0.f;
#pragma unroll
        for (int n = 0; n < N_; ++n) {
            sdelta[n] = sdl * daux[n];
            cum += sdelta[n];
            xf[n] = cum + DMIN_v * (float)n - D_v * (float)(n + 1);
        }
    }

    // ---- power readout (af[.][0] = afp.x) ----
    float hp_[8];
#pragma unroll
    for (int j = 0; j < 8; ++j) {
        float s = ro[108 + j];
#pragma unroll
        for (int n = 0; n < N_; ++n) s = fmaf(afp[n].x, ro[76 + j * 4 + n], s);
        hp_[j] = fmaxf(s, 0.f);
    }
    float paux[N_];
    float sump = 1e-6f;
#pragma unroll
    for (int n = 0; n < N_; ++n) {
        float s = ro[148 + n];
#pragma unroll
        for (int j = 0; j < 8; ++j) s = fmaf(hp_[j], ro[116 + n * 8 + j], s);
        paux[n] = fmaxf(s, 0.001f);
        sump += paux[n];
    }
    const float pscale = PMAX_v * frcp(fmaxf(PMAX_v, sump));

    // ---- stores: scaled_power (B,4) | scaled_delta (B,4) | final_positions (B,4,3)
    float4 sp;
    sp.x = pscale * paux[0]; sp.y = pscale * paux[1];
    sp.z = pscale * paux[2]; sp.w = pscale * paux[3];
    ((float4*)out)[b] = sp;

    float4 sdv;
    sdv.x = sdelta[0]; sdv.y = sdelta[1]; sdv.z = sdelta[2]; sdv.w = sdelta[3];
    ((float4*)(out + (size_t)4 * BATCH))[b] = sdv;

    float* pos = out + (size_t)8 * BATCH + (size_t)b * 12;
    float4 p0, p1, p2;
    p0.x = xf[0]; p0.y = 0.f;   p0.z = HZ_v;  p0.w = xf[1];
    p1.x = 0.f;   p1.y = HZ_v;  p1.z = xf[2]; p1.w = 0.f;
    p2.x = HZ_v;  p2.y = xf[3]; p2.z = 0.f;   p2.w = HZ_v;
    ((float4*)pos)[0] = p0;
    ((float4*)pos)[1] = p1;
    ((float4*)pos)[2] = p2;
}

extern "C" void kernel_launch(void* const* d_in, const int* in_sizes, int n_in,
                              void* d_out, int out_size, void* d_ws, size_t ws_size,
                              hipStream_t stream) {
    const float* users      = (const float*)d_in[0];
    const float* delta_init = (const float*)d_in[1];
    const float* power_init = (const float*)d_in[2];
    const float* Wu    = (const float*)d_in[3];
    const float* Wa    = (const float*)d_in[4];
    const float* We    = (const float*)d_in[5];
    const float* av    = (const float*)d_in[6];
    const float* Wres  = (const float*)d_in[7];
    const float* lnu_g = (const float*)d_in[8];
    const float* lnu_b = (const float*)d_in[9];
    const float* lna_g = (const float*)d_in[10];
    const float* lna_b = (const float*)d_in[11];
    const float* mu_w1 = (const float*)d_in[12];
    const float* mu_b1 = (const float*)d_in[13];
    const float* mu_w2 = (const float*)d_in[14];
    const float* mu_b2 = (const float*)d_in[15];
    const float* ma_w1 = (const float*)d_in[16];
    const float* ma_b1 = (const float*)d_in[17];
    const float* ma_w2 = (const float*)d_in[18];
    const float* ma_b2 = (const float*)d_in[19];
    const float* rd_w1 = (const float*)d_in[20];
    const float* rd_b1 = (const float*)d_in[21];
    const float* rd_w2 = (const float*)d_in[22];
    const float* rd_b2 = (const float*)d_in[23];
    const float* rp_w1 = (const float*)d_in[24];
    const float* rp_b1 = (const float*)d_in[25];
    const float* rp_w2 = (const float*)d_in[26];
    const float* rp_b2 = (const float*)d_in[27];
    float* ws  = (float*)d_ws;
    float* out = (float*)d_out;

    hipLaunchKernelGGL(pack_weights, dim3((TOTF + 255) / 256), dim3(256), 0, stream,
                       Wu, Wa, We, av, Wres, lnu_g, lnu_b, lna_g, lna_b,
                       mu_w1, mu_b1, mu_w2, mu_b2, ma_w1, ma_b1, ma_w2, ma_b2,
                       rd_w1, rd_b1, rd_w2, rd_b2, rp_w1, rp_b1, rp_w2, rp_b2, ws);

    hipLaunchKernelGGL(bgat_fwd, dim3(BATCH / 256), dim3(256), 0, stream,
                       ws, users, delta_init, power_init, out);
}